// Round 3
// baseline (1818.664 us; speedup 1.0000x reference)
//
#include <hip/hip_runtime.h>

// Fused flash-style softmax(Q V^T) V, B=4, NQ=NK=4096, D=1024, fp32 in/out.
// Round 3: round-1 verified structure + fp16 single-product MFMA + register
// double-prefetch of V tiles. All LDS layouts identical to the round-1 kernel
// that passed (absmax 0.031).
// - Block = 32 q-rows, 8 waves, wave w owns d-slice [128w,128w+128).
// - S^T = mfma(V, Q) swapped so both operands are d-contiguous.
// - V staged per-wave in LDS (vhi_off swizzle), PV B-frags via scalar u16 reads.

#define NB   4
#define NQL  4096
#define NKL  4096
#define DIM  1024
#define BQ   32
#define BK   32
#define NW   8
#define DSL  128
#define NT   (NKL / BK)
#define LOG2E 1.44269504088896340736f

typedef float f32x4 __attribute__((ext_vector_type(4)));
typedef _Float16 f16x8 __attribute__((ext_vector_type(8)));
typedef short s16x8 __attribute__((ext_vector_type(8)));

union Frag { f16x8 v; s16x8 s; _Float16 h[8]; };

// V LDS addressing (round-1 verified): wave-private [BK][DSL] f16 tile,
// slot-swizzled so b128 stage-writes are bank-optimal and u16 PV reads OK.
__device__ __forceinline__ int vhi_off(int k, int dloc) {  // byte offset in wave region
    int slot = ((k & 7) + 2 * ((k >> 3) & 3)) & 7;
    return k * (DSL * 2) + ((dloc * 2) ^ (slot * 16));
}

// S-partial index permutation (round-1 verified).
__device__ __forceinline__ int sp_idx(int q, int k) {
    int kp = (k & 3) | (((k >> 4) & 1) << 2) | (((k >> 3) & 1) << 3) | (((k >> 2) & 1) << 4);
    return (q + kp) & 31;
}

__global__ __launch_bounds__(512, 2)
void attn_f16(const float* __restrict__ Qg, const float* __restrict__ Vg,
              float* __restrict__ Og) {
    __shared__ __align__(16) short vhi_s[NW * BK * DSL];  // 64 KB
    __shared__ float spart[NW][BQ][BK];                   // 32 KB
    __shared__ __align__(16) short pbuf[BQ * BK];         // 2 KB (fp16 P)
    __shared__ float mrun[BQ], lrun[BQ], arun[BQ];

    const int tid = (int)threadIdx.x;
    const int l   = tid & 63;
    const int w   = tid >> 6;
    const int l15 = l & 15;
    const int lg  = l >> 4;

    const int b  = (int)blockIdx.x >> 7;
    const int qt = (int)blockIdx.x & 127;
    const int q0 = qt * BQ;
    const int dw = w * DSL;

    if (tid < BQ) { mrun[tid] = -3e38f; lrun[tid] = 0.f; arun[tid] = 1.f; }

    // Q fragments (B-operand): lane holds Q[q0+qb*16+l15][dw+dc*32+lg*8 .. +7] fp16
    f16x8 qf[2][4];
#pragma unroll
    for (int qb = 0; qb < 2; ++qb)
#pragma unroll
        for (int dc = 0; dc < 4; ++dc) {
            const float* qp = Qg + (size_t)(b * NQL + q0 + qb * 16 + l15) * DIM
                            + dw + dc * 32 + lg * 8;
            f32x4 x0 = *(const f32x4*)qp;
            f32x4 x1 = *(const f32x4*)(qp + 4);
            f16x8 a;
#pragma unroll
            for (int j = 0; j < 4; ++j) { a[j] = (_Float16)x0[j]; a[j + 4] = (_Float16)x1[j]; }
            qf[qb][dc] = a;
        }

    f32x4 oacc[2][8];
#pragma unroll
    for (int qb = 0; qb < 2; ++qb)
#pragma unroll
        for (int dg = 0; dg < 8; ++dg)
            oacc[qb][dg] = (f32x4){0.f, 0.f, 0.f, 0.f};

    char* vbase = (char*)&vhi_s[w * (BK * DSL)];

    f32x4 sacc[2][2];
    f32x4 hA[4][2], hB[4][2];  // register prefetch buffers: half-tile each

    auto loadhalf = [&](f32x4 (&buf)[4][2], int kt_, int kb) {
        const float* vp = Vg + (size_t)(b * NKL + kt_ * BK + kb * 16 + l15) * DIM
                        + dw + lg * 8;
#pragma unroll
        for (int dc = 0; dc < 4; ++dc) {
            buf[dc][0] = *(const f32x4*)(vp + dc * 32);
            buf[dc][1] = *(const f32x4*)(vp + dc * 32 + 4);
        }
    };

    auto computehalf = [&](f32x4 (&buf)[4][2], int kb) {
        const int kvl = kb * 16 + l15;
#pragma unroll
        for (int dc = 0; dc < 4; ++dc) {
            Frag fa;
#pragma unroll
            for (int j = 0; j < 4; ++j) {
                fa.h[j]     = (_Float16)buf[dc][0][j];
                fa.h[j + 4] = (_Float16)buf[dc][1][j];
            }
            *(s16x8*)(vbase + vhi_off(kvl, dc * 32 + lg * 8)) = fa.s;
            sacc[kb][0] = __builtin_amdgcn_mfma_f32_16x16x32_f16(fa.v, qf[0][dc], sacc[kb][0], 0, 0, 0);
            sacc[kb][1] = __builtin_amdgcn_mfma_f32_16x16x32_f16(fa.v, qf[1][dc], sacc[kb][1], 0, 0, 0);
        }
    };

    // softmax lane assignment: q = 4w+lg, k = l15 and l15+16
    const int qsm = 4 * w + lg;
    const int rk0 = sp_idx(qsm, l15);
    const int rk1 = sp_idx(qsm, l15 + 16);

    loadhalf(hA, 0, 0);
    loadhalf(hB, 0, 1);
    __syncthreads();

    for (int kt = 0; kt < NT; ++kt) {
#pragma unroll
        for (int kb = 0; kb < 2; ++kb)
#pragma unroll
            for (int qb = 0; qb < 2; ++qb)
                sacc[kb][qb] = (f32x4){0.f, 0.f, 0.f, 0.f};

        const int ktn = (kt + 1 < NT) ? kt + 1 : NT - 1;
        computehalf(hA, 0);
        loadhalf(hA, ktn, 0);   // next tile, in flight over hB compute + softmax + PV
        computehalf(hB, 1);
        loadhalf(hB, ktn, 1);

        // Write S^T partials (acc layout: row k = kb*16+4*lg+r, col q = qb*16+l15)
#pragma unroll
        for (int kb = 0; kb < 2; ++kb)
#pragma unroll
            for (int qb = 0; qb < 2; ++qb)
#pragma unroll
                for (int r = 0; r < 4; ++r) {
                    int k = kb * 16 + lg * 4 + r;
                    int q = qb * 16 + l15;
                    spart[w][q][sp_idx(q, k)] = sacc[kb][qb][r];
                }
        __syncthreads();  // B1

        // Phase 2: reduce partials over waves, online softmax for q = qsm
        {
            float s0 = 0.f, s1 = 0.f;
#pragma unroll
            for (int wv = 0; wv < NW; ++wv) {
                s0 += spart[wv][qsm][rk0];
                s1 += spart[wv][qsm][rk1];
            }
            float mloc = fmaxf(s0, s1);
#pragma unroll
            for (int off = 1; off < 16; off <<= 1)
                mloc = fmaxf(mloc, __shfl_xor(mloc, off));
            float mold = mrun[qsm];
            float mnew = fmaxf(mold, mloc);
            float p0 = exp2f((s0 - mnew) * LOG2E);
            float p1 = exp2f((s1 - mnew) * LOG2E);
            float rs = p0 + p1;
#pragma unroll
            for (int off = 1; off < 16; off <<= 1)
                rs += __shfl_xor(rs, off);
            float alpha = exp2f((mold - mnew) * LOG2E);
            if (l15 == 0) {
                mrun[qsm] = mnew;
                lrun[qsm] = alpha * lrun[qsm] + rs;
                arun[qsm] = alpha;
            }
            pbuf[qsm * BK + l15]      = __builtin_bit_cast(short, (_Float16)p0);
            pbuf[qsm * BK + l15 + 16] = __builtin_bit_cast(short, (_Float16)p1);
        }
        __syncthreads();  // B2: P/alpha/m/l visible; guards S-partial reuse

        // Phase 3: rescale O by alpha, then O += P * V
        float av[2][4];
#pragma unroll
        for (int qb = 0; qb < 2; ++qb)
#pragma unroll
            for (int r = 0; r < 4; ++r)
                av[qb][r] = arun[qb * 16 + lg * 4 + r];
#pragma unroll
        for (int qb = 0; qb < 2; ++qb)
#pragma unroll
            for (int dg = 0; dg < 8; ++dg)
#pragma unroll
                for (int r = 0; r < 4; ++r)
                    oacc[qb][dg][r] *= av[qb][r];

        Frag pf[2];
#pragma unroll
        for (int qb = 0; qb < 2; ++qb)
            pf[qb].s = *(const s16x8*)(pbuf + (qb * 16 + l15) * BK + lg * 8);

#pragma unroll
        for (int dg = 0; dg < 8; ++dg) {
            Frag bf;
#pragma unroll
            for (int j = 0; j < 8; ++j) {
                int k = lg * 8 + j;
                bf.h[j] = *(const _Float16*)(vbase + vhi_off(k, dg * 16 + l15));
            }
#pragma unroll
            for (int qb = 0; qb < 2; ++qb)
                oacc[qb][dg] = __builtin_amdgcn_mfma_f32_16x16x32_f16(
                    pf[qb].v, bf.v, oacc[qb][dg], 0, 0, 0);
        }
    }

    // Epilogue: normalize by l, store fp32
#pragma unroll
    for (int qb = 0; qb < 2; ++qb) {
        float il[4];
#pragma unroll
        for (int r = 0; r < 4; ++r)
            il[r] = 1.0f / lrun[qb * 16 + lg * 4 + r];
#pragma unroll
        for (int dg = 0; dg < 8; ++dg)
#pragma unroll
            for (int r = 0; r < 4; ++r) {
                int q = q0 + qb * 16 + lg * 4 + r;
                int d = dw + dg * 16 + l15;
                Og[(size_t)(b * NQL + q) * DIM + d] = oacc[qb][dg][r] * il[r];
            }
    }
}

extern "C" void kernel_launch(void* const* d_in, const int* in_sizes, int n_in,
                              void* d_out, int out_size, void* d_ws, size_t ws_size,
                              hipStream_t stream) {
    const float* Q = (const float*)d_in[0];
    const float* V = (const float*)d_in[1];
    float* O = (float*)d_out;
    (void)in_sizes; (void)n_in; (void)out_size; (void)d_ws; (void)ws_size;
    dim3 grid(NB * (NQL / BQ));  // 512 blocks
    dim3 block(NW * 64);         // 512 threads
    attn_f16<<<grid, block, 0, stream>>>(Q, V, O);
}